// Round 15
// baseline (283.038 us; speedup 1.0000x reference)
//
#include <hip/hip_runtime.h>

#define NTOK 100352   // 8*112*112
#define NPB  12544    // tokens per batch (112*112)
#define CH   256

typedef unsigned short u16;
typedef float f32x4 __attribute__((ext_vector_type(4)));
typedef short bfrag __attribute__((ext_vector_type(8)));   // 8 bf16 = 4 VGPRs

static __device__ __forceinline__ u16 f2bf(float f) {
    union { float f; unsigned u; } v; v.f = f;
    unsigned r = v.u + 0x7FFFu + ((v.u >> 16) & 1u);   // RNE
    return (u16)(r >> 16);
}
static __device__ __forceinline__ float bf2f(u16 h) {
    union { unsigned u; float f; } v; v.u = ((unsigned)h) << 16;
    return v.f;
}
static __device__ __forceinline__ unsigned pk2(float a, float b) {
    return (unsigned)f2bf(a) | ((unsigned)f2bf(b) << 16);
}
// async global->LDS, 16B/lane; LDS dest = wave-uniform base + lane*16 (linear)
static __device__ __forceinline__ void gl16(const u16* g, u16* l) {
    __builtin_amdgcn_global_load_lds(
        (const __attribute__((address_space(1))) void*)g,
        (__attribute__((address_space(3))) void*)l, 16, 0, 0);
}
// branch-free GELU: erf via Abramowitz-Stegun 7.1.26 (|err|<1.5e-7)
static __device__ __forceinline__ float gelu_fast(float v) {
    float z = v * 0.70710678118654752f;
    float a = fabsf(z);
    float t = 1.0f / fmaf(0.3275911f, a, 1.0f);
    float p = t * fmaf(t, fmaf(t, fmaf(t, fmaf(t, 1.061405429f, -1.453152027f),
                                        1.421413741f), -0.284496736f), 0.254829592f);
    float e = __expf(-a * a);
    float erfa = fmaf(-p, e, 1.0f);
    float erfz = (z < 0.f) ? -erfa : erfa;
    return 0.5f * v * (1.0f + erfz);
}

// ---------------- K0: weight prep (fp32 -> bf16, fold q scale) ----------------
__global__ __launch_bounds__(256)
void swa_prep(const float* __restrict__ wq, const float* __restrict__ wk,
              const float* __restrict__ wv, const float* __restrict__ wm,
              u16* __restrict__ wcat, u16* __restrict__ wmb)
{
    int i0 = blockIdx.x * 256 + threadIdx.x;
    int stride = gridDim.x * 256;
    for (int i = i0; i < 768 * 256; i += stride) {
        int r = i >> 8, c = i & 255;
        float v;
        if (r < 256)      v = wq[r * 256 + c] * 0.0625f;      // fold d^-0.5 = 1/16
        else if (r < 512) v = wk[(r - 256) * 256 + c];
        else              v = wv[(r - 512) * 256 + c];
        wcat[i] = f2bf(v);
    }
    for (int i = i0; i < 256 * 256; i += stride) wmb[i] = f2bf(wm[i]);
}

// ---------------- K1a: roll + LN -> xn (bf16), one wave per token ----------------
__global__ __launch_bounds__(256)
void swa_ln(const float* __restrict__ x,
            const float* __restrict__ ln_g, const float* __restrict__ ln_b,
            u16* __restrict__ xn)
{
    const int lane = threadIdx.x & 63;
    const int wid  = threadIdx.x >> 6;
    f32x4 lg = *reinterpret_cast<const f32x4*>(ln_g + lane * 4);
    f32x4 lb = *reinterpret_cast<const f32x4*>(ln_b + lane * 4);

    const int wtok0 = (blockIdx.x * 4 + wid) * 16;
    for (int i = 0; i < 16; ++i) {
        int tok = wtok0 + i;
        int b_  = tok / NPB;
        int rem = tok - b_ * NPB;
        int h = rem / 112, w = rem - h * 112;
        int h0 = h - 3 + ((h < 3) ? 112 : 0);         // shifted read
        int w0 = w - 3 + ((w < 3) ? 112 : 0);
        f32x4 v = *reinterpret_cast<const f32x4*>(x + (size_t)(b_ * NPB + h0 * 112 + w0) * CH + lane * 4);
        float s  = v[0] + v[1] + v[2] + v[3];
        float sq = v[0]*v[0] + v[1]*v[1] + v[2]*v[2] + v[3]*v[3];
        #pragma unroll
        for (int m = 1; m < 64; m <<= 1) { s += __shfl_xor(s, m); sq += __shfl_xor(sq, m); }
        float mu  = s * (1.0f / 256.0f);
        float var = sq * (1.0f / 256.0f) - mu * mu;
        float inv = 1.0f / sqrtf(var + 1e-5f);
        uint2 p;
        p.x = pk2((v[0] - mu) * inv * lg[0] + lb[0], (v[1] - mu) * inv * lg[1] + lb[1]);
        p.y = pk2((v[2] - mu) * inv * lg[2] + lb[2], (v[3] - mu) * inv * lg[3] + lb[3]);
        *reinterpret_cast<uint2*>(xn + (size_t)tok * CH + lane * 4) = p;
    }
}

// ---------------- K1b: k,v GEMM; W-half resident in LDS, barrier-free loop --------
__global__ __launch_bounds__(512)
void swa_kv(const u16* __restrict__ xn, const u16* __restrict__ wcat,
            const float* __restrict__ bk, const float* __restrict__ bv,
            u16* __restrict__ kbuf, u16* __restrict__ vbuf)
{
    __shared__ u16 wt[128 * 256];                 // 64 KB

    const int tid  = threadIdx.x;
    const int lane = tid & 63;
    const int wid  = tid >> 6;
    const int r16  = lane & 15, g4 = lane >> 4;
    const int swz   = (blockIdx.x & 7) * 196 + (blockIdx.x >> 3);   // 1568 = 8*196
    const int type  = swz / 392;                  // 0,1 = k halves; 2,3 = v halves
    const int strip = swz % 392;
    const int sec   = 1 + (type >> 1);
    const int half  = type & 1;
    const int tok0w = strip * 256 + wid * 32;
    const int wrow0 = sec * 256 + half * 128;

    #pragma unroll
    for (int rr2 = 0; rr2 < 8; ++rr2) {
        int o   = (tid + rr2 * 512) * 16;
        int row = o >> 9;
        int cp  = (o >> 4) & 31;
        int c   = (cp & 24) | ((cp & 7) ^ (row & 7));
        gl16(wcat + (size_t)(wrow0 + row) * CH + c * 8, wt + o / 2);
    }

    bfrag bx[2][8];
    #pragma unroll
    for (int fj = 0; fj < 2; ++fj) {
        const u16* xp = xn + (size_t)(tok0w + fj * 16 + r16) * CH + g4 * 8;
        #pragma unroll
        for (int kb = 0; kb < 8; ++kb)
            bx[fj][kb] = *reinterpret_cast<const bfrag*>(xp + kb * 32);
    }

    u16*         outp = (sec == 1) ? kbuf : vbuf;
    const float* bsp  = (sec == 1) ? bk : bv;

    __syncthreads();                              // W staged; only barrier

    #pragma unroll
    for (int p = 0; p < 4; ++p) {                 // 4 passes x 32 ch
        f32x4 acc[2][2];
        #pragma unroll
        for (int ct = 0; ct < 2; ++ct) { acc[ct][0] = (f32x4)0.f; acc[ct][1] = (f32x4)0.f; }
        #pragma unroll
        for (int kk = 0; kk < 8; ++kk) {
            bfrag af[2];
            #pragma unroll
            for (int ct = 0; ct < 2; ++ct) {
                int row = p * 32 + ct * 16 + r16;
                int cc  = kk * 4 + g4;
                int cp  = (cc & 24) | ((cc & 7) ^ (row & 7));
                af[ct]  = *reinterpret_cast<const bfrag*>((const char*)wt + row * 512 + cp * 16);
            }
            #pragma unroll
            for (int ct = 0; ct < 2; ++ct) {
                acc[ct][0] = __builtin_amdgcn_mfma_f32_16x16x32_bf16(af[ct], bx[0][kk], acc[ct][0], 0, 0, 0);
                acc[ct][1] = __builtin_amdgcn_mfma_f32_16x16x32_bf16(af[ct], bx[1][kk], acc[ct][1], 0, 0, 0);
            }
        }
        #pragma unroll
        for (int ct = 0; ct < 2; ++ct) {
            int ch = half * 128 + p * 32 + ct * 16 + g4 * 4;   // section-local channel
            f32x4 bb = *reinterpret_cast<const f32x4*>(bsp + ch);
            #pragma unroll
            for (int fj = 0; fj < 2; ++fj) {
                int tok = tok0w + fj * 16 + r16;
                uint2 pkk;
                pkk.x = pk2(acc[ct][fj][0] + bb[0], acc[ct][fj][1] + bb[1]);
                pkk.y = pk2(acc[ct][fj][2] + bb[2], acc[ct][fj][3] + bb[3]);
                *reinterpret_cast<uint2*>(outp + (size_t)tok * CH + ch) = pkk;
            }
        }
    }
}

// ---------------- K1c: q GEMM in-place over xn; full section resident ------------
__global__ __launch_bounds__(512)
void swa_q(u16* xnq, const u16* __restrict__ wcat, const float* __restrict__ bq)
{
    __shared__ u16 wt[256 * 256];                 // 128 KB (q section)

    const int tid  = threadIdx.x;
    const int lane = tid & 63;
    const int wid  = tid >> 6;
    const int r16  = lane & 15, g4 = lane >> 4;
    const int strip = (blockIdx.x & 7) * 49 + (blockIdx.x >> 3);   // 392 = 8*49
    const int tok0w = strip * 256 + wid * 32;

    #pragma unroll
    for (int rr2 = 0; rr2 < 16; ++rr2) {
        int o   = (tid + rr2 * 512) * 16;
        int row = o >> 9;
        int cp  = (o >> 4) & 31;
        int c   = (cp & 24) | ((cp & 7) ^ (row & 7));
        gl16(wcat + (size_t)row * CH + c * 8, wt + o / 2);
    }

    bfrag bx[2][8];
    #pragma unroll
    for (int fj = 0; fj < 2; ++fj) {
        const u16* xp = xnq + (size_t)(tok0w + fj * 16 + r16) * CH + g4 * 8;
        #pragma unroll
        for (int kb = 0; kb < 8; ++kb)
            bx[fj][kb] = *reinterpret_cast<const bfrag*>(xp + kb * 32);
    }

    __syncthreads();                              // W staged + all xn reads done

    #pragma unroll
    for (int p = 0; p < 8; ++p) {                 // 8 passes x 32 ch
        f32x4 acc[2][2];
        #pragma unroll
        for (int ct = 0; ct < 2; ++ct) { acc[ct][0] = (f32x4)0.f; acc[ct][1] = (f32x4)0.f; }
        #pragma unroll
        for (int kk = 0; kk < 8; ++kk) {
            bfrag af[2];
            #pragma unroll
            for (int ct = 0; ct < 2; ++ct) {
                int row = p * 32 + ct * 16 + r16;
                int cc  = kk * 4 + g4;
                int cp  = (cc & 24) | ((cc & 7) ^ (row & 7));
                af[ct]  = *reinterpret_cast<const bfrag*>((const char*)wt + row * 512 + cp * 16);
            }
            #pragma unroll
            for (int ct = 0; ct < 2; ++ct) {
                acc[ct][0] = __builtin_amdgcn_mfma_f32_16x16x32_bf16(af[ct], bx[0][kk], acc[ct][0], 0, 0, 0);
                acc[ct][1] = __builtin_amdgcn_mfma_f32_16x16x32_bf16(af[ct], bx[1][kk], acc[ct][1], 0, 0, 0);
            }
        }
        #pragma unroll
        for (int ct = 0; ct < 2; ++ct) {
            int ch = p * 32 + ct * 16 + g4 * 4;
            f32x4 bb = *reinterpret_cast<const f32x4*>(bq + ch);
            #pragma unroll
            for (int fj = 0; fj < 2; ++fj) {
                int tok = tok0w + fj * 16 + r16;
                uint2 pkk;
                pkk.x = pk2(acc[ct][fj][0] + bb[0] * 0.0625f, acc[ct][fj][1] + bb[1] * 0.0625f);
                pkk.y = pk2(acc[ct][fj][2] + bb[2] * 0.0625f, acc[ct][fj][3] + bb[3] * 0.0625f);
                *reinterpret_cast<uint2*>(xnq + (size_t)tok * CH + ch) = pkk;
            }
        }
    }
}

// ---------------- K2: local attention + on-the-fly k-normalization ----------------
__global__ __launch_bounds__(256)
void swa_attn(const u16* qbuf, const u16* kbuf, const u16* vbuf, u16* obuf)
{
    __shared__ float plds[4][16][17];
    const int tid  = threadIdx.x;
    const int lane = tid & 63;
    const int wid  = tid >> 6;
    const int win  = blockIdx.x * 4 + wid;
    const int iw   = win % 1792;
    const int base = win * 7;
    const int r16  = lane & 15;
    const int g4   = lane >> 4;

    int qrow = base + r16; if (qrow > NTOK - 1) qrow = NTOK - 1;
    int krow = base - 7 + r16; if (krow < 0) krow = 0;
    const u16* qp = qbuf + (size_t)qrow * CH + g4 * 8;
    const u16* kp = kbuf + (size_t)krow * CH + g4 * 8;

    bfrag kf[8];
    #pragma unroll
    for (int kk = 0; kk < 8; ++kk) kf[kk] = *reinterpret_cast<const bfrag*>(kp + kk * 32);
    float sq = 0.f;
    #pragma unroll
    for (int kk = 0; kk < 8; ++kk)
        #pragma unroll
        for (int e = 0; e < 8; ++e) { float kv = bf2f((u16)kf[kk][e]); sq += kv * kv; }
    sq += __shfl_xor(sq, 16); sq += __shfl_xor(sq, 32);
    float invk = 1.0f / fmaxf(sqrtf(sq), 1e-12f);

    f32x4 s4 = {0.f, 0.f, 0.f, 0.f};
    #pragma unroll
    for (int kk = 0; kk < 8; ++kk) {
        bfrag a = *reinterpret_cast<const bfrag*>(qp + kk * 32);
        s4 = __builtin_amdgcn_mfma_f32_16x16x32_bf16(a, kf[kk], s4, 0, 0, 0);
    }

    const int  j     = r16;
    const bool first = (iw == 0);
    #pragma unroll
    for (int rr = 0; rr < 4; ++rr) {
        int i = g4 * 4 + rr;
        float s = s4[rr] * invk;
        if (j == i + 7) s = -5.0e4f;
        if (j > i + 7 || j >= 14 || (first && j < 7)) s = -3.0e38f;
        s4[rr] = s;
    }
    f32x4 mx = s4;
    #pragma unroll
    for (int off = 8; off; off >>= 1) {
        #pragma unroll
        for (int rr = 0; rr < 4; ++rr) mx[rr] = fmaxf(mx[rr], __shfl_xor(mx[rr], off));
    }
    f32x4 p;
    #pragma unroll
    for (int rr = 0; rr < 4; ++rr) p[rr] = __expf(s4[rr] - mx[rr]);
    f32x4 sm = p;
    #pragma unroll
    for (int off = 8; off; off >>= 1) {
        #pragma unroll
        for (int rr = 0; rr < 4; ++rr) sm[rr] += __shfl_xor(sm[rr], off);
    }
    #pragma unroll
    for (int rr = 0; rr < 4; ++rr) plds[wid][g4 * 4 + rr][j] = p[rr] / sm[rr];
    __syncthreads();

    f32x4 zero4 = {0.f, 0.f, 0.f, 0.f};
    f32x4 oa[7];
    #pragma unroll
    for (int i = 0; i < 7; ++i) oa[i] = zero4;
    for (int jj = 0; jj < 14; ++jj) {
        int vrow = base - 7 + jj;
        if (vrow < 0) vrow = 0;
        ushort4 vr = *reinterpret_cast<const ushort4*>(vbuf + (size_t)vrow * CH + lane * 4);
        f32x4 vvv; vvv[0] = bf2f(vr.x); vvv[1] = bf2f(vr.y); vvv[2] = bf2f(vr.z); vvv[3] = bf2f(vr.w);
        #pragma unroll
        for (int i = 0; i < 7; ++i) {
            float pp = plds[wid][i][jj];
            oa[i][0] += pp * vvv[0]; oa[i][1] += pp * vvv[1];
            oa[i][2] += pp * vvv[2]; oa[i][3] += pp * vvv[3];
        }
    }
    #pragma unroll
    for (int i = 0; i < 7; ++i) {
        ushort4 o; o.x = f2bf(oa[i][0]); o.y = f2bf(oa[i][1]); o.z = f2bf(oa[i][2]); o.w = f2bf(oa[i][3]);
        *reinterpret_cast<ushort4*>(obuf + (size_t)(base + i) * CH + lane * 4) = o;
    }
}

// ---------------- K3: mlp7 — no rsd LDS; epilogue re-reads x+attn (L2-hot) --------
// 3136 blocks x 32 tokens; 256 thr. LDS ~17.9 KB -> 8 blocks/CU residency.
__global__ __launch_bounds__(256)
void swa_mlp7(const float* __restrict__ x, const u16* __restrict__ abuf,
              const float* __restrict__ ln_g, const float* __restrict__ ln_b,
              const u16* __restrict__ wmb, const float* __restrict__ mbias,
              float* __restrict__ out)
{
    __shared__ u16 xs[32 * 264];                  // LN'd, bf16 (row stride 528 B)
    __shared__ float bias[256];
    const int tid  = threadIdx.x;
    const int lane = tid & 63;
    const int wid  = tid >> 6;
    const int tok0 = blockIdx.x * 32;
    const int r16  = lane & 15;
    const int g4   = lane >> 4;

    bias[tid] = mbias[tid];

    // ---- parallel stage: 8 threads per token, 32 tokens at once ----
    {
        const int r   = tid >> 3;                 // token row 0..31
        const int sub = tid & 7;
        int tok = tok0 + r;
        int b_  = tok / NPB, rem = tok - b_ * NPB;
        int h = rem / 112, w = rem - h * 112;
        int hs = h + 3;  if (hs >= 112) hs -= 112;    // unshift
        int ws_ = w + 3; if (ws_ >= 112) ws_ -= 112;
        const float* xrow = x + (size_t)tok * CH;
        const u16*   arow = abuf + (size_t)(b_ * NPB + hs * 112 + ws_) * CH;

        f32x4 rv[8];
        float s = 0.f, sq = 0.f;
        #pragma unroll
        for (int j = 0; j < 8; ++j) {
            int cf = sub + 8 * j;                 // 16B chunk (4 channels)
            f32x4   xv = *reinterpret_cast<const f32x4*>(xrow + cf * 4);
            ushort4 av = *reinterpret_cast<const ushort4*>(arow + cf * 4);
            rv[j][0] = xv[0] + bf2f(av.x); rv[j][1] = xv[1] + bf2f(av.y);
            rv[j][2] = xv[2] + bf2f(av.z); rv[j][3] = xv[3] + bf2f(av.w);
            s  += rv[j][0] + rv[j][1] + rv[j][2] + rv[j][3];
            sq += rv[j][0]*rv[j][0] + rv[j][1]*rv[j][1] + rv[j][2]*rv[j][2] + rv[j][3]*rv[j][3];
        }
        s += __shfl_xor(s, 1); sq += __shfl_xor(sq, 1);
        s += __shfl_xor(s, 2); sq += __shfl_xor(sq, 2);
        s += __shfl_xor(s, 4); sq += __shfl_xor(sq, 4);
        float mu  = s * (1.0f / 256.0f);
        float var = sq * (1.0f / 256.0f) - mu * mu;
        float inv = 1.0f / sqrtf(var + 1e-5f);

        char* xb = (char*)xs;
        #pragma unroll
        for (int j = 0; j < 8; ++j) {
            int cf = sub + 8 * j;
            f32x4 g = *reinterpret_cast<const f32x4*>(ln_g + cf * 4);
            f32x4 b = *reinterpret_cast<const f32x4*>(ln_b + cf * 4);
            uint2 px;
            px.x = pk2((rv[j][0]-mu)*inv*g[0]+b[0], (rv[j][1]-mu)*inv*g[1]+b[1]);
            px.y = pk2((rv[j][2]-mu)*inv*g[2]+b[2], (rv[j][3]-mu)*inv*g[3]+b[3]);
            *reinterpret_cast<uint2*>(xb + r * 528 + cf * 8) = px;
        }
    }
    __syncthreads();                              // only barrier

    f32x4 acc[4][2];
    #pragma unroll
    for (int i = 0; i < 4; ++i) { acc[i][0] = (f32x4)0.f; acc[i][1] = (f32x4)0.f; }

    #pragma unroll
    for (int kk = 0; kk < 8; ++kk) {
        bfrag b0 = *reinterpret_cast<const bfrag*>((const char*)xs + r16 * 528 + kk * 64 + g4 * 16);
        bfrag b1 = *reinterpret_cast<const bfrag*>((const char*)xs + (16 + r16) * 528 + kk * 64 + g4 * 16);
        #pragma unroll
        for (int ct = 0; ct < 4; ++ct) {
            bfrag wf = *reinterpret_cast<const bfrag*>(wmb + (size_t)(wid * 64 + ct * 16 + r16) * CH + kk * 32 + g4 * 8);
            acc[ct][0] = __builtin_amdgcn_mfma_f32_16x16x32_bf16(wf, b0, acc[ct][0], 0, 0, 0);
            acc[ct][1] = __builtin_amdgcn_mfma_f32_16x16x32_bf16(wf, b1, acc[ct][1], 0, 0, 0);
        }
    }

    // epilogue: lane owns (token tokL, 4 ch); re-derive rsd from x + attn (L2-hot)
    #pragma unroll
    for (int rt = 0; rt < 2; ++rt) {
        int tokL = rt * 16 + r16;
        int tok  = tok0 + tokL;
        int b_   = tok / NPB, rem = tok - b_ * NPB;
        int h = rem / 112, w = rem - h * 112;
        int hs = h + 3;  if (hs >= 112) hs -= 112;
        int ws_ = w + 3; if (ws_ >= 112) ws_ -= 112;
        const float* xrow = x + (size_t)tok * CH;
        const u16*   arow = abuf + (size_t)(b_ * NPB + hs * 112 + ws_) * CH;
        #pragma unroll
        for (int ct = 0; ct < 4; ++ct) {
            int ch = wid * 64 + ct * 16 + g4 * 4;
            f32x4 bb = *reinterpret_cast<const f32x4*>(&bias[ch]);
            f32x4   xr = *reinterpret_cast<const f32x4*>(xrow + ch);
            ushort4 ar = *reinterpret_cast<const ushort4*>(arow + ch);
            f32x4 vv;
            vv[0] = gelu_fast(acc[ct][rt][0] + bb[0]) + xr[0] + bf2f(ar.x);
            vv[1] = gelu_fast(acc[ct][rt][1] + bb[1]) + xr[1] + bf2f(ar.y);
            vv[2] = gelu_fast(acc[ct][rt][2] + bb[2]) + xr[2] + bf2f(ar.z);
            vv[3] = gelu_fast(acc[ct][rt][3] + bb[3]) + xr[3] + bf2f(ar.w);
            *reinterpret_cast<f32x4*>(out + (size_t)tok * CH + ch) = vv;
        }
    }
}

extern "C" void kernel_launch(void* const* d_in, const int* in_sizes, int n_in,
                              void* d_out, int out_size, void* d_ws, size_t ws_size,
                              hipStream_t stream)
{
    const float* x     = (const float*)d_in[0];
    const float* ln_g  = (const float*)d_in[1];
    const float* ln_b  = (const float*)d_in[2];
    const float* wq_w  = (const float*)d_in[3];
    const float* wq_b  = (const float*)d_in[4];
    const float* wk_w  = (const float*)d_in[5];
    const float* wk_b  = (const float*)d_in[6];
    const float* wv_w  = (const float*)d_in[7];
    const float* wv_b  = (const float*)d_in[8];
    const float* mlp_w = (const float*)d_in[9];
    const float* mlp_b = (const float*)d_in[10];

    char* ws = (char*)d_ws;
    u16* wcat = (u16*)ws;                       // 768*256 bf16
    u16* wmb  = (u16*)(ws + 393216);            // 256*256 bf16
    u16* xnq  = (u16*)(ws + 524288);            // xn -> q (in-place) -> attn output
    u16* kbuf = (u16*)d_out;                    // k,v live in d_out until mlp rewrites it
    u16* vbuf = (u16*)d_out + (size_t)NTOK * CH;

    swa_prep <<<256,  256, 0, stream>>>(wq_w, wk_w, wv_w, mlp_w, wcat, wmb);
    swa_ln   <<<1568, 256, 0, stream>>>(x, ln_g, ln_b, xnq);
    swa_kv   <<<1568, 512, 0, stream>>>(xnq, wcat, wk_b, wv_b, kbuf, vbuf);
    swa_q    <<<392,  512, 0, stream>>>(xnq, wcat, wq_b);
    swa_attn <<<3584, 256, 0, stream>>>(xnq, kbuf, vbuf, xnq);
    swa_mlp7 <<<3136, 256, 0, stream>>>(x, xnq, ln_g, ln_b, wmb, mlp_b, (float*)d_out);
}

// Round 16
// 270.973 us; speedup vs baseline: 1.0445x; 1.0445x over previous
//
#include <hip/hip_runtime.h>

#define NTOK 100352   // 8*112*112
#define NPB  12544    // tokens per batch (112*112)
#define CH   256

typedef unsigned short u16;
typedef float f32x4 __attribute__((ext_vector_type(4)));
typedef short bfrag __attribute__((ext_vector_type(8)));   // 8 bf16 = 4 VGPRs

static __device__ __forceinline__ u16 f2bf(float f) {
    union { float f; unsigned u; } v; v.f = f;
    unsigned r = v.u + 0x7FFFu + ((v.u >> 16) & 1u);   // RNE
    return (u16)(r >> 16);
}
static __device__ __forceinline__ float bf2f(u16 h) {
    union { unsigned u; float f; } v; v.u = ((unsigned)h) << 16;
    return v.f;
}
static __device__ __forceinline__ unsigned pk2(float a, float b) {
    return (unsigned)f2bf(a) | ((unsigned)f2bf(b) << 16);
}
// async global->LDS, 16B/lane; LDS dest = wave-uniform base + lane*16 (linear)
static __device__ __forceinline__ void gl16(const u16* g, u16* l) {
    __builtin_amdgcn_global_load_lds(
        (const __attribute__((address_space(1))) void*)g,
        (__attribute__((address_space(3))) void*)l, 16, 0, 0);
}
// branch-free GELU: erf via Abramowitz-Stegun 7.1.26 (|err|<1.5e-7)
static __device__ __forceinline__ float gelu_fast(float v) {
    float z = v * 0.70710678118654752f;
    float a = fabsf(z);
    float t = 1.0f / fmaf(0.3275911f, a, 1.0f);
    float p = t * fmaf(t, fmaf(t, fmaf(t, fmaf(t, 1.061405429f, -1.453152027f),
                                        1.421413741f), -0.284496736f), 0.254829592f);
    float e = __expf(-a * a);
    float erfa = fmaf(-p, e, 1.0f);
    float erfz = (z < 0.f) ? -erfa : erfa;
    return 0.5f * v * (1.0f + erfz);
}

// ---------------- K0: weight prep (fp32 -> bf16, fold q scale) ----------------
__global__ __launch_bounds__(256)
void swa_prep(const float* __restrict__ wq, const float* __restrict__ wk,
              const float* __restrict__ wv, const float* __restrict__ wm,
              u16* __restrict__ wcat, u16* __restrict__ wmb)
{
    int i0 = blockIdx.x * 256 + threadIdx.x;
    int stride = gridDim.x * 256;
    for (int i = i0; i < 768 * 256; i += stride) {
        int r = i >> 8, c = i & 255;
        float v;
        if (r < 256)      v = wq[r * 256 + c] * 0.0625f;      // fold d^-0.5 = 1/16
        else if (r < 512) v = wk[(r - 256) * 256 + c];
        else              v = wv[(r - 512) * 256 + c];
        wcat[i] = f2bf(v);
    }
    for (int i = i0; i < 256 * 256; i += stride) wmb[i] = f2bf(wm[i]);
}

// ---------------- K1a: roll + LN -> xn (bf16), one wave per token ----------------
__global__ __launch_bounds__(256)
void swa_ln(const float* __restrict__ x,
            const float* __restrict__ ln_g, const float* __restrict__ ln_b,
            u16* __restrict__ xn)
{
    const int lane = threadIdx.x & 63;
    const int wid  = threadIdx.x >> 6;
    f32x4 lg = *reinterpret_cast<const f32x4*>(ln_g + lane * 4);
    f32x4 lb = *reinterpret_cast<const f32x4*>(ln_b + lane * 4);

    const int wtok0 = (blockIdx.x * 4 + wid) * 16;
    for (int i = 0; i < 16; ++i) {
        int tok = wtok0 + i;
        int b_  = tok / NPB;
        int rem = tok - b_ * NPB;
        int h = rem / 112, w = rem - h * 112;
        int h0 = h - 3 + ((h < 3) ? 112 : 0);         // shifted read
        int w0 = w - 3 + ((w < 3) ? 112 : 0);
        f32x4 v = *reinterpret_cast<const f32x4*>(x + (size_t)(b_ * NPB + h0 * 112 + w0) * CH + lane * 4);
        float s  = v[0] + v[1] + v[2] + v[3];
        float sq = v[0]*v[0] + v[1]*v[1] + v[2]*v[2] + v[3]*v[3];
        #pragma unroll
        for (int m = 1; m < 64; m <<= 1) { s += __shfl_xor(s, m); sq += __shfl_xor(sq, m); }
        float mu  = s * (1.0f / 256.0f);
        float var = sq * (1.0f / 256.0f) - mu * mu;
        float inv = 1.0f / sqrtf(var + 1e-5f);
        uint2 p;
        p.x = pk2((v[0] - mu) * inv * lg[0] + lb[0], (v[1] - mu) * inv * lg[1] + lb[1]);
        p.y = pk2((v[2] - mu) * inv * lg[2] + lb[2], (v[3] - mu) * inv * lg[3] + lb[3]);
        *reinterpret_cast<uint2*>(xn + (size_t)tok * CH + lane * 4) = p;
    }
}

// ---------------- K1b: k,v GEMM; W-half resident in LDS, barrier-free loop --------
__global__ __launch_bounds__(512)
void swa_kv(const u16* __restrict__ xn, const u16* __restrict__ wcat,
            const float* __restrict__ bk, const float* __restrict__ bv,
            u16* __restrict__ kbuf, u16* __restrict__ vbuf)
{
    __shared__ u16 wt[128 * 256];                 // 64 KB

    const int tid  = threadIdx.x;
    const int lane = tid & 63;
    const int wid  = tid >> 6;
    const int r16  = lane & 15, g4 = lane >> 4;
    const int swz   = (blockIdx.x & 7) * 196 + (blockIdx.x >> 3);   // 1568 = 8*196
    const int type  = swz / 392;                  // 0,1 = k halves; 2,3 = v halves
    const int strip = swz % 392;
    const int sec   = 1 + (type >> 1);
    const int half  = type & 1;
    const int tok0w = strip * 256 + wid * 32;
    const int wrow0 = sec * 256 + half * 128;

    #pragma unroll
    for (int rr2 = 0; rr2 < 8; ++rr2) {
        int o   = (tid + rr2 * 512) * 16;
        int row = o >> 9;
        int cp  = (o >> 4) & 31;
        int c   = (cp & 24) | ((cp & 7) ^ (row & 7));
        gl16(wcat + (size_t)(wrow0 + row) * CH + c * 8, wt + o / 2);
    }

    bfrag bx[2][8];
    #pragma unroll
    for (int fj = 0; fj < 2; ++fj) {
        const u16* xp = xn + (size_t)(tok0w + fj * 16 + r16) * CH + g4 * 8;
        #pragma unroll
        for (int kb = 0; kb < 8; ++kb)
            bx[fj][kb] = *reinterpret_cast<const bfrag*>(xp + kb * 32);
    }

    u16*         outp = (sec == 1) ? kbuf : vbuf;
    const float* bsp  = (sec == 1) ? bk : bv;

    __syncthreads();                              // W staged; only barrier

    #pragma unroll
    for (int p = 0; p < 4; ++p) {                 // 4 passes x 32 ch
        f32x4 acc[2][2];
        #pragma unroll
        for (int ct = 0; ct < 2; ++ct) { acc[ct][0] = (f32x4)0.f; acc[ct][1] = (f32x4)0.f; }
        #pragma unroll
        for (int kk = 0; kk < 8; ++kk) {
            bfrag af[2];
            #pragma unroll
            for (int ct = 0; ct < 2; ++ct) {
                int row = p * 32 + ct * 16 + r16;
                int cc  = kk * 4 + g4;
                int cp  = (cc & 24) | ((cc & 7) ^ (row & 7));
                af[ct]  = *reinterpret_cast<const bfrag*>((const char*)wt + row * 512 + cp * 16);
            }
            #pragma unroll
            for (int ct = 0; ct < 2; ++ct) {
                acc[ct][0] = __builtin_amdgcn_mfma_f32_16x16x32_bf16(af[ct], bx[0][kk], acc[ct][0], 0, 0, 0);
                acc[ct][1] = __builtin_amdgcn_mfma_f32_16x16x32_bf16(af[ct], bx[1][kk], acc[ct][1], 0, 0, 0);
            }
        }
        #pragma unroll
        for (int ct = 0; ct < 2; ++ct) {
            int ch = half * 128 + p * 32 + ct * 16 + g4 * 4;   // section-local channel
            f32x4 bb = *reinterpret_cast<const f32x4*>(bsp + ch);
            #pragma unroll
            for (int fj = 0; fj < 2; ++fj) {
                int tok = tok0w + fj * 16 + r16;
                uint2 pkk;
                pkk.x = pk2(acc[ct][fj][0] + bb[0], acc[ct][fj][1] + bb[1]);
                pkk.y = pk2(acc[ct][fj][2] + bb[2], acc[ct][fj][3] + bb[3]);
                *reinterpret_cast<uint2*>(outp + (size_t)tok * CH + ch) = pkk;
            }
        }
    }
}

// ---------------- K1c: q GEMM in-place over xn; full W resident; 784 blocks -------
// 784 blocks (=8*98) x 128 tokens; 512 thr / 8 waves x 16 tokens. Reduces the
// residency-round tail of the old 392-block version (1.53 -> 3.06 rounds).
// In-place safe: all xn reads precede the single barrier; q stores after.
__global__ __launch_bounds__(512)
void swa_q2(u16* xnq, const u16* __restrict__ wcat, const float* __restrict__ bq)
{
    __shared__ u16 wt[256 * 256];                 // 128 KB (q section)

    const int tid  = threadIdx.x;
    const int lane = tid & 63;
    const int wid  = tid >> 6;                    // 0..7
    const int r16  = lane & 15, g4 = lane >> 4;
    const int strip = (blockIdx.x & 7) * 98 + (blockIdx.x >> 3);   // 784 = 8*98
    const int tok0w = strip * 128 + wid * 16;

    #pragma unroll
    for (int rr2 = 0; rr2 < 16; ++rr2) {
        int o   = (tid + rr2 * 512) * 16;
        int row = o >> 9;
        int cp  = (o >> 4) & 31;
        int c   = (cp & 24) | ((cp & 7) ^ (row & 7));
        gl16(wcat + (size_t)row * CH + c * 8, wt + o / 2);
    }

    bfrag bx[8];
    {
        const u16* xp = xnq + (size_t)(tok0w + r16) * CH + g4 * 8;
        #pragma unroll
        for (int kb = 0; kb < 8; ++kb)
            bx[kb] = *reinterpret_cast<const bfrag*>(xp + kb * 32);
    }

    __syncthreads();                              // W staged + all xn reads done

    #pragma unroll
    for (int p = 0; p < 8; ++p) {                 // 8 passes x 32 ch
        f32x4 acc[2];
        acc[0] = (f32x4)0.f; acc[1] = (f32x4)0.f;
        #pragma unroll
        for (int kk = 0; kk < 8; ++kk) {
            bfrag af[2];
            #pragma unroll
            for (int ct = 0; ct < 2; ++ct) {
                int row = p * 32 + ct * 16 + r16;
                int cc  = kk * 4 + g4;
                int cp  = (cc & 24) | ((cc & 7) ^ (row & 7));
                af[ct]  = *reinterpret_cast<const bfrag*>((const char*)wt + row * 512 + cp * 16);
            }
            acc[0] = __builtin_amdgcn_mfma_f32_16x16x32_bf16(af[0], bx[kk], acc[0], 0, 0, 0);
            acc[1] = __builtin_amdgcn_mfma_f32_16x16x32_bf16(af[1], bx[kk], acc[1], 0, 0, 0);
        }
        #pragma unroll
        for (int ct = 0; ct < 2; ++ct) {
            int ch = p * 32 + ct * 16 + g4 * 4;
            f32x4 bb = *reinterpret_cast<const f32x4*>(bq + ch);
            int tok = tok0w + r16;
            uint2 pkk;
            pkk.x = pk2(acc[ct][0] + bb[0] * 0.0625f, acc[ct][1] + bb[1] * 0.0625f);
            pkk.y = pk2(acc[ct][2] + bb[2] * 0.0625f, acc[ct][3] + bb[3] * 0.0625f);
            *reinterpret_cast<uint2*>(xnq + (size_t)tok * CH + ch) = pkk;
        }
    }
}

// ---------------- K2: local attention + on-the-fly k-normalization ----------------
__global__ __launch_bounds__(256)
void swa_attn(const u16* qbuf, const u16* kbuf, const u16* vbuf, u16* obuf)
{
    __shared__ float plds[4][16][17];
    const int tid  = threadIdx.x;
    const int lane = tid & 63;
    const int wid  = tid >> 6;
    const int win  = blockIdx.x * 4 + wid;
    const int iw   = win % 1792;
    const int base = win * 7;
    const int r16  = lane & 15;
    const int g4   = lane >> 4;

    int qrow = base + r16; if (qrow > NTOK - 1) qrow = NTOK - 1;
    int krow = base - 7 + r16; if (krow < 0) krow = 0;
    const u16* qp = qbuf + (size_t)qrow * CH + g4 * 8;
    const u16* kp = kbuf + (size_t)krow * CH + g4 * 8;

    bfrag kf[8];
    #pragma unroll
    for (int kk = 0; kk < 8; ++kk) kf[kk] = *reinterpret_cast<const bfrag*>(kp + kk * 32);
    float sq = 0.f;
    #pragma unroll
    for (int kk = 0; kk < 8; ++kk)
        #pragma unroll
        for (int e = 0; e < 8; ++e) { float kv = bf2f((u16)kf[kk][e]); sq += kv * kv; }
    sq += __shfl_xor(sq, 16); sq += __shfl_xor(sq, 32);
    float invk = 1.0f / fmaxf(sqrtf(sq), 1e-12f);

    f32x4 s4 = {0.f, 0.f, 0.f, 0.f};
    #pragma unroll
    for (int kk = 0; kk < 8; ++kk) {
        bfrag a = *reinterpret_cast<const bfrag*>(qp + kk * 32);
        s4 = __builtin_amdgcn_mfma_f32_16x16x32_bf16(a, kf[kk], s4, 0, 0, 0);
    }

    const int  j     = r16;
    const bool first = (iw == 0);
    #pragma unroll
    for (int rr = 0; rr < 4; ++rr) {
        int i = g4 * 4 + rr;
        float s = s4[rr] * invk;
        if (j == i + 7) s = -5.0e4f;
        if (j > i + 7 || j >= 14 || (first && j < 7)) s = -3.0e38f;
        s4[rr] = s;
    }
    f32x4 mx = s4;
    #pragma unroll
    for (int off = 8; off; off >>= 1) {
        #pragma unroll
        for (int rr = 0; rr < 4; ++rr) mx[rr] = fmaxf(mx[rr], __shfl_xor(mx[rr], off));
    }
    f32x4 p;
    #pragma unroll
    for (int rr = 0; rr < 4; ++rr) p[rr] = __expf(s4[rr] - mx[rr]);
    f32x4 sm = p;
    #pragma unroll
    for (int off = 8; off; off >>= 1) {
        #pragma unroll
        for (int rr = 0; rr < 4; ++rr) sm[rr] += __shfl_xor(sm[rr], off);
    }
    #pragma unroll
    for (int rr = 0; rr < 4; ++rr) plds[wid][g4 * 4 + rr][j] = p[rr] / sm[rr];
    __syncthreads();

    f32x4 zero4 = {0.f, 0.f, 0.f, 0.f};
    f32x4 oa[7];
    #pragma unroll
    for (int i = 0; i < 7; ++i) oa[i] = zero4;
    for (int jj = 0; jj < 14; ++jj) {
        int vrow = base - 7 + jj;
        if (vrow < 0) vrow = 0;
        ushort4 vr = *reinterpret_cast<const ushort4*>(vbuf + (size_t)vrow * CH + lane * 4);
        f32x4 vvv; vvv[0] = bf2f(vr.x); vvv[1] = bf2f(vr.y); vvv[2] = bf2f(vr.z); vvv[3] = bf2f(vr.w);
        #pragma unroll
        for (int i = 0; i < 7; ++i) {
            float pp = plds[wid][i][jj];
            oa[i][0] += pp * vvv[0]; oa[i][1] += pp * vvv[1];
            oa[i][2] += pp * vvv[2]; oa[i][3] += pp * vvv[3];
        }
    }
    #pragma unroll
    for (int i = 0; i < 7; ++i) {
        ushort4 o; o.x = f2bf(oa[i][0]); o.y = f2bf(oa[i][1]); o.z = f2bf(oa[i][2]); o.w = f2bf(oa[i][3]);
        *reinterpret_cast<ushort4*>(obuf + (size_t)(base + i) * CH + lane * 4) = o;
    }
}

// ---------------- K3: mlp6 — parallel stage (8 thr/token), bf16 rsd, fast gelu ----
__global__ __launch_bounds__(256)
void swa_mlp6(const float* __restrict__ x, const u16* __restrict__ abuf,
              const float* __restrict__ ln_g, const float* __restrict__ ln_b,
              const u16* __restrict__ wmb, const float* __restrict__ mbias,
              float* __restrict__ out)
{
    __shared__ u16 xs[32 * 264];                  // LN'd, bf16 (row stride 528 B)
    __shared__ u16 rsdl[32 * 264];                // residual, bf16
    __shared__ float bias[256];
    const int tid  = threadIdx.x;
    const int lane = tid & 63;
    const int wid  = tid >> 6;
    const int tok0 = blockIdx.x * 32;
    const int r16  = lane & 15;
    const int g4   = lane >> 4;

    bias[tid] = mbias[tid];

    // ---- parallel stage: 8 threads per token, 32 tokens at once ----
    {
        const int r   = tid >> 3;                 // token row 0..31
        const int sub = tid & 7;
        int tok = tok0 + r;
        int b_  = tok / NPB, rem = tok - b_ * NPB;
        int h = rem / 112, w = rem - h * 112;
        int hs = h + 3;  if (hs >= 112) hs -= 112;    // unshift
        int ws_ = w + 3; if (ws_ >= 112) ws_ -= 112;
        const float* xrow = x + (size_t)tok * CH;
        const u16*   arow = abuf + (size_t)(b_ * NPB + hs * 112 + ws_) * CH;

        f32x4 rv[8];
        float s = 0.f, sq = 0.f;
        #pragma unroll
        for (int j = 0; j < 8; ++j) {
            int cf = sub + 8 * j;                 // 16B chunk (4 channels)
            f32x4   xv = *reinterpret_cast<const f32x4*>(xrow + cf * 4);
            ushort4 av = *reinterpret_cast<const ushort4*>(arow + cf * 4);
            rv[j][0] = xv[0] + bf2f(av.x); rv[j][1] = xv[1] + bf2f(av.y);
            rv[j][2] = xv[2] + bf2f(av.z); rv[j][3] = xv[3] + bf2f(av.w);
            s  += rv[j][0] + rv[j][1] + rv[j][2] + rv[j][3];
            sq += rv[j][0]*rv[j][0] + rv[j][1]*rv[j][1] + rv[j][2]*rv[j][2] + rv[j][3]*rv[j][3];
        }
        s += __shfl_xor(s, 1); sq += __shfl_xor(sq, 1);
        s += __shfl_xor(s, 2); sq += __shfl_xor(sq, 2);
        s += __shfl_xor(s, 4); sq += __shfl_xor(sq, 4);
        float mu  = s * (1.0f / 256.0f);
        float var = sq * (1.0f / 256.0f) - mu * mu;
        float inv = 1.0f / sqrtf(var + 1e-5f);

        char* xb = (char*)xs;
        char* rb = (char*)rsdl;
        #pragma unroll
        for (int j = 0; j < 8; ++j) {
            int cf = sub + 8 * j;
            f32x4 g = *reinterpret_cast<const f32x4*>(ln_g + cf * 4);
            f32x4 b = *reinterpret_cast<const f32x4*>(ln_b + cf * 4);
            uint2 px, pr;
            px.x = pk2((rv[j][0]-mu)*inv*g[0]+b[0], (rv[j][1]-mu)*inv*g[1]+b[1]);
            px.y = pk2((rv[j][2]-mu)*inv*g[2]+b[2], (rv[j][3]-mu)*inv*g[3]+b[3]);
            pr.x = pk2(rv[j][0], rv[j][1]);
            pr.y = pk2(rv[j][2], rv[j][3]);
            *reinterpret_cast<uint2*>(xb + r * 528 + cf * 8) = px;
            *reinterpret_cast<uint2*>(rb + r * 528 + cf * 8) = pr;
        }
    }
    __syncthreads();                              // only barrier

    f32x4 acc[4][2];
    #pragma unroll
    for (int i = 0; i < 4; ++i) { acc[i][0] = (f32x4)0.f; acc[i][1] = (f32x4)0.f; }

    #pragma unroll
    for (int kk = 0; kk < 8; ++kk) {
        bfrag b0 = *reinterpret_cast<const bfrag*>((const char*)xs + r16 * 528 + kk * 64 + g4 * 16);
        bfrag b1 = *reinterpret_cast<const bfrag*>((const char*)xs + (16 + r16) * 528 + kk * 64 + g4 * 16);
        #pragma unroll
        for (int ct = 0; ct < 4; ++ct) {
            bfrag wf = *reinterpret_cast<const bfrag*>(wmb + (size_t)(wid * 64 + ct * 16 + r16) * CH + kk * 32 + g4 * 8);
            acc[ct][0] = __builtin_amdgcn_mfma_f32_16x16x32_bf16(wf, b0, acc[ct][0], 0, 0, 0);
            acc[ct][1] = __builtin_amdgcn_mfma_f32_16x16x32_bf16(wf, b1, acc[ct][1], 0, 0, 0);
        }
    }

    #pragma unroll
    for (int ct = 0; ct < 4; ++ct) {
        int ch = wid * 64 + ct * 16 + g4 * 4;
        f32x4 bb = *reinterpret_cast<const f32x4*>(&bias[ch]);
        #pragma unroll
        for (int rt = 0; rt < 2; ++rt) {
            int tokL = rt * 16 + r16;
            ushort4 rbv = *reinterpret_cast<const ushort4*>((const char*)rsdl + tokL * 528 + ch * 2);
            f32x4 vv;
            vv[0] = gelu_fast(acc[ct][rt][0] + bb[0]) + bf2f(rbv.x);
            vv[1] = gelu_fast(acc[ct][rt][1] + bb[1]) + bf2f(rbv.y);
            vv[2] = gelu_fast(acc[ct][rt][2] + bb[2]) + bf2f(rbv.z);
            vv[3] = gelu_fast(acc[ct][rt][3] + bb[3]) + bf2f(rbv.w);
            *reinterpret_cast<f32x4*>(out + (size_t)(tok0 + tokL) * CH + ch) = vv;
        }
    }
}

extern "C" void kernel_launch(void* const* d_in, const int* in_sizes, int n_in,
                              void* d_out, int out_size, void* d_ws, size_t ws_size,
                              hipStream_t stream)
{
    const float* x     = (const float*)d_in[0];
    const float* ln_g  = (const float*)d_in[1];
    const float* ln_b  = (const float*)d_in[2];
    const float* wq_w  = (const float*)d_in[3];
    const float* wq_b  = (const float*)d_in[4];
    const float* wk_w  = (const float*)d_in[5];
    const float* wk_b  = (const float*)d_in[6];
    const float* wv_w  = (const float*)d_in[7];
    const float* wv_b  = (const float*)d_in[8];
    const float* mlp_w = (const float*)d_in[9];
    const float* mlp_b = (const float*)d_in[10];

    char* ws = (char*)d_ws;
    u16* wcat = (u16*)ws;                       // 768*256 bf16
    u16* wmb  = (u16*)(ws + 393216);            // 256*256 bf16
    u16* xnq  = (u16*)(ws + 524288);            // xn -> q (in-place) -> attn output
    u16* kbuf = (u16*)d_out;                    // k,v live in d_out until mlp rewrites it
    u16* vbuf = (u16*)d_out + (size_t)NTOK * CH;

    swa_prep <<<256,  256, 0, stream>>>(wq_w, wk_w, wv_w, mlp_w, wcat, wmb);
    swa_ln   <<<1568, 256, 0, stream>>>(x, ln_g, ln_b, xnq);
    swa_kv   <<<1568, 512, 0, stream>>>(xnq, wcat, wk_b, wv_b, kbuf, vbuf);
    swa_q2   <<<784,  512, 0, stream>>>(xnq, wcat, wq_b);
    swa_attn <<<3584, 256, 0, stream>>>(xnq, kbuf, vbuf, xnq);
    swa_mlp6 <<<3136, 256, 0, stream>>>(x, xnq, ln_g, ln_b, wmb, mlp_b, (float*)d_out);
}

// Round 17
// 249.650 us; speedup vs baseline: 1.1337x; 1.0854x over previous
//
#include <hip/hip_runtime.h>

#define NTOK 100352   // 8*112*112
#define NPB  12544    // tokens per batch (112*112)
#define CH   256

typedef unsigned short u16;
typedef float f32x4 __attribute__((ext_vector_type(4)));
typedef short bfrag __attribute__((ext_vector_type(8)));   // 8 bf16 = 4 VGPRs

static __device__ __forceinline__ u16 f2bf(float f) {
    union { float f; unsigned u; } v; v.f = f;
    unsigned r = v.u + 0x7FFFu + ((v.u >> 16) & 1u);   // RNE
    return (u16)(r >> 16);
}
static __device__ __forceinline__ float bf2f(u16 h) {
    union { unsigned u; float f; } v; v.u = ((unsigned)h) << 16;
    return v.f;
}
static __device__ __forceinline__ unsigned pk2(float a, float b) {
    return (unsigned)f2bf(a) | ((unsigned)f2bf(b) << 16);
}
// async global->LDS, 16B/lane; LDS dest = wave-uniform base + lane*16 (linear)
static __device__ __forceinline__ void gl16(const u16* g, u16* l) {
    __builtin_amdgcn_global_load_lds(
        (const __attribute__((address_space(1))) void*)g,
        (__attribute__((address_space(3))) void*)l, 16, 0, 0);
}
// branch-free GELU: erf via Abramowitz-Stegun 7.1.26 (|err|<1.5e-7)
static __device__ __forceinline__ float gelu_fast(float v) {
    float z = v * 0.70710678118654752f;
    float a = fabsf(z);
    float t = 1.0f / fmaf(0.3275911f, a, 1.0f);
    float p = t * fmaf(t, fmaf(t, fmaf(t, fmaf(t, 1.061405429f, -1.453152027f),
                                        1.421413741f), -0.284496736f), 0.254829592f);
    float e = __expf(-a * a);
    float erfa = fmaf(-p, e, 1.0f);
    float erfz = (z < 0.f) ? -erfa : erfa;
    return 0.5f * v * (1.0f + erfz);
}

// ---------------- K0: weight prep (fp32 -> bf16, fold q scale) ----------------
__global__ __launch_bounds__(256)
void swa_prep(const float* __restrict__ wq, const float* __restrict__ wk,
              const float* __restrict__ wv, const float* __restrict__ wm,
              u16* __restrict__ wcat, u16* __restrict__ wmb)
{
    int i0 = blockIdx.x * 256 + threadIdx.x;
    int stride = gridDim.x * 256;
    for (int i = i0; i < 768 * 256; i += stride) {
        int r = i >> 8, c = i & 255;
        float v;
        if (r < 256)      v = wq[r * 256 + c] * 0.0625f;      // fold d^-0.5 = 1/16
        else if (r < 512) v = wk[(r - 256) * 256 + c];
        else              v = wv[(r - 512) * 256 + c];
        wcat[i] = f2bf(v);
    }
    for (int i = i0; i < 256 * 256; i += stride) wmb[i] = f2bf(wm[i]);
}

// ---------------- K1a: roll + LN -> xn (bf16), one wave per token ----------------
__global__ __launch_bounds__(256)
void swa_ln(const float* __restrict__ x,
            const float* __restrict__ ln_g, const float* __restrict__ ln_b,
            u16* __restrict__ xn)
{
    const int lane = threadIdx.x & 63;
    const int wid  = threadIdx.x >> 6;
    f32x4 lg = *reinterpret_cast<const f32x4*>(ln_g + lane * 4);
    f32x4 lb = *reinterpret_cast<const f32x4*>(ln_b + lane * 4);

    const int wtok0 = (blockIdx.x * 4 + wid) * 16;
    for (int i = 0; i < 16; ++i) {
        int tok = wtok0 + i;
        int b_  = tok / NPB;
        int rem = tok - b_ * NPB;
        int h = rem / 112, w = rem - h * 112;
        int h0 = h - 3 + ((h < 3) ? 112 : 0);         // shifted read
        int w0 = w - 3 + ((w < 3) ? 112 : 0);
        f32x4 v = *reinterpret_cast<const f32x4*>(x + (size_t)(b_ * NPB + h0 * 112 + w0) * CH + lane * 4);
        float s  = v[0] + v[1] + v[2] + v[3];
        float sq = v[0]*v[0] + v[1]*v[1] + v[2]*v[2] + v[3]*v[3];
        #pragma unroll
        for (int m = 1; m < 64; m <<= 1) { s += __shfl_xor(s, m); sq += __shfl_xor(sq, m); }
        float mu  = s * (1.0f / 256.0f);
        float var = sq * (1.0f / 256.0f) - mu * mu;
        float inv = 1.0f / sqrtf(var + 1e-5f);
        uint2 p;
        p.x = pk2((v[0] - mu) * inv * lg[0] + lb[0], (v[1] - mu) * inv * lg[1] + lb[1]);
        p.y = pk2((v[2] - mu) * inv * lg[2] + lb[2], (v[3] - mu) * inv * lg[3] + lb[3]);
        *reinterpret_cast<uint2*>(xn + (size_t)tok * CH + lane * 4) = p;
    }
}

// ---------------- K1b: k,v GEMM; W-half resident in LDS, barrier-free loop --------
__global__ __launch_bounds__(512)
void swa_kv(const u16* __restrict__ xn, const u16* __restrict__ wcat,
            const float* __restrict__ bk, const float* __restrict__ bv,
            u16* __restrict__ kbuf, u16* __restrict__ vbuf)
{
    __shared__ u16 wt[128 * 256];                 // 64 KB

    const int tid  = threadIdx.x;
    const int lane = tid & 63;
    const int wid  = tid >> 6;
    const int r16  = lane & 15, g4 = lane >> 4;
    const int swz   = (blockIdx.x & 7) * 196 + (blockIdx.x >> 3);   // 1568 = 8*196
    const int type  = swz / 392;                  // 0,1 = k halves; 2,3 = v halves
    const int strip = swz % 392;
    const int sec   = 1 + (type >> 1);
    const int half  = type & 1;
    const int tok0w = strip * 256 + wid * 32;
    const int wrow0 = sec * 256 + half * 128;

    #pragma unroll
    for (int rr2 = 0; rr2 < 8; ++rr2) {
        int o   = (tid + rr2 * 512) * 16;
        int row = o >> 9;
        int cp  = (o >> 4) & 31;
        int c   = (cp & 24) | ((cp & 7) ^ (row & 7));
        gl16(wcat + (size_t)(wrow0 + row) * CH + c * 8, wt + o / 2);
    }

    bfrag bx[2][8];
    #pragma unroll
    for (int fj = 0; fj < 2; ++fj) {
        const u16* xp = xn + (size_t)(tok0w + fj * 16 + r16) * CH + g4 * 8;
        #pragma unroll
        for (int kb = 0; kb < 8; ++kb)
            bx[fj][kb] = *reinterpret_cast<const bfrag*>(xp + kb * 32);
    }

    u16*         outp = (sec == 1) ? kbuf : vbuf;
    const float* bsp  = (sec == 1) ? bk : bv;

    __syncthreads();                              // W staged; only barrier

    #pragma unroll
    for (int p = 0; p < 4; ++p) {                 // 4 passes x 32 ch
        f32x4 acc[2][2];
        #pragma unroll
        for (int ct = 0; ct < 2; ++ct) { acc[ct][0] = (f32x4)0.f; acc[ct][1] = (f32x4)0.f; }
        #pragma unroll
        for (int kk = 0; kk < 8; ++kk) {
            bfrag af[2];
            #pragma unroll
            for (int ct = 0; ct < 2; ++ct) {
                int row = p * 32 + ct * 16 + r16;
                int cc  = kk * 4 + g4;
                int cp  = (cc & 24) | ((cc & 7) ^ (row & 7));
                af[ct]  = *reinterpret_cast<const bfrag*>((const char*)wt + row * 512 + cp * 16);
            }
            #pragma unroll
            for (int ct = 0; ct < 2; ++ct) {
                acc[ct][0] = __builtin_amdgcn_mfma_f32_16x16x32_bf16(af[ct], bx[0][kk], acc[ct][0], 0, 0, 0);
                acc[ct][1] = __builtin_amdgcn_mfma_f32_16x16x32_bf16(af[ct], bx[1][kk], acc[ct][1], 0, 0, 0);
            }
        }
        #pragma unroll
        for (int ct = 0; ct < 2; ++ct) {
            int ch = half * 128 + p * 32 + ct * 16 + g4 * 4;   // section-local channel
            f32x4 bb = *reinterpret_cast<const f32x4*>(bsp + ch);
            #pragma unroll
            for (int fj = 0; fj < 2; ++fj) {
                int tok = tok0w + fj * 16 + r16;
                uint2 pkk;
                pkk.x = pk2(acc[ct][fj][0] + bb[0], acc[ct][fj][1] + bb[1]);
                pkk.y = pk2(acc[ct][fj][2] + bb[2], acc[ct][fj][3] + bb[3]);
                *reinterpret_cast<uint2*>(outp + (size_t)tok * CH + ch) = pkk;
            }
        }
    }
}

// ---------------- K1c: q GEMM in-place over xn; full section resident ------------
__global__ __launch_bounds__(512)
void swa_q(u16* xnq, const u16* __restrict__ wcat, const float* __restrict__ bq)
{
    __shared__ u16 wt[256 * 256];                 // 128 KB (q section)

    const int tid  = threadIdx.x;
    const int lane = tid & 63;
    const int wid  = tid >> 6;
    const int r16  = lane & 15, g4 = lane >> 4;
    const int strip = (blockIdx.x & 7) * 49 + (blockIdx.x >> 3);   // 392 = 8*49
    const int tok0w = strip * 256 + wid * 32;

    #pragma unroll
    for (int rr2 = 0; rr2 < 16; ++rr2) {
        int o   = (tid + rr2 * 512) * 16;
        int row = o >> 9;
        int cp  = (o >> 4) & 31;
        int c   = (cp & 24) | ((cp & 7) ^ (row & 7));
        gl16(wcat + (size_t)row * CH + c * 8, wt + o / 2);
    }

    bfrag bx[2][8];
    #pragma unroll
    for (int fj = 0; fj < 2; ++fj) {
        const u16* xp = xnq + (size_t)(tok0w + fj * 16 + r16) * CH + g4 * 8;
        #pragma unroll
        for (int kb = 0; kb < 8; ++kb)
            bx[fj][kb] = *reinterpret_cast<const bfrag*>(xp + kb * 32);
    }

    __syncthreads();                              // W staged + all xn reads done

    #pragma unroll
    for (int p = 0; p < 8; ++p) {                 // 8 passes x 32 ch
        f32x4 acc[2][2];
        #pragma unroll
        for (int ct = 0; ct < 2; ++ct) { acc[ct][0] = (f32x4)0.f; acc[ct][1] = (f32x4)0.f; }
        #pragma unroll
        for (int kk = 0; kk < 8; ++kk) {
            bfrag af[2];
            #pragma unroll
            for (int ct = 0; ct < 2; ++ct) {
                int row = p * 32 + ct * 16 + r16;
                int cc  = kk * 4 + g4;
                int cp  = (cc & 24) | ((cc & 7) ^ (row & 7));
                af[ct]  = *reinterpret_cast<const bfrag*>((const char*)wt + row * 512 + cp * 16);
            }
            #pragma unroll
            for (int ct = 0; ct < 2; ++ct) {
                acc[ct][0] = __builtin_amdgcn_mfma_f32_16x16x32_bf16(af[ct], bx[0][kk], acc[ct][0], 0, 0, 0);
                acc[ct][1] = __builtin_amdgcn_mfma_f32_16x16x32_bf16(af[ct], bx[1][kk], acc[ct][1], 0, 0, 0);
            }
        }
        #pragma unroll
        for (int ct = 0; ct < 2; ++ct) {
            int ch = p * 32 + ct * 16 + g4 * 4;
            f32x4 bb = *reinterpret_cast<const f32x4*>(bq + ch);
            #pragma unroll
            for (int fj = 0; fj < 2; ++fj) {
                int tok = tok0w + fj * 16 + r16;
                uint2 pkk;
                pkk.x = pk2(acc[ct][fj][0] + bb[0] * 0.0625f, acc[ct][fj][1] + bb[1] * 0.0625f);
                pkk.y = pk2(acc[ct][fj][2] + bb[2] * 0.0625f, acc[ct][fj][3] + bb[3] * 0.0625f);
                *reinterpret_cast<uint2*>(xnq + (size_t)tok * CH + ch) = pkk;
            }
        }
    }
}

// ---------------- K2: local attention + on-the-fly k-normalization ----------------
__global__ __launch_bounds__(256)
void swa_attn(const u16* qbuf, const u16* kbuf, const u16* vbuf, u16* obuf)
{
    __shared__ float plds[4][16][17];
    const int tid  = threadIdx.x;
    const int lane = tid & 63;
    const int wid  = tid >> 6;
    const int win  = blockIdx.x * 4 + wid;
    const int iw   = win % 1792;
    const int base = win * 7;
    const int r16  = lane & 15;
    const int g4   = lane >> 4;

    int qrow = base + r16; if (qrow > NTOK - 1) qrow = NTOK - 1;
    int krow = base - 7 + r16; if (krow < 0) krow = 0;
    const u16* qp = qbuf + (size_t)qrow * CH + g4 * 8;
    const u16* kp = kbuf + (size_t)krow * CH + g4 * 8;

    bfrag kf[8];
    #pragma unroll
    for (int kk = 0; kk < 8; ++kk) kf[kk] = *reinterpret_cast<const bfrag*>(kp + kk * 32);
    float sq = 0.f;
    #pragma unroll
    for (int kk = 0; kk < 8; ++kk)
        #pragma unroll
        for (int e = 0; e < 8; ++e) { float kv = bf2f((u16)kf[kk][e]); sq += kv * kv; }
    sq += __shfl_xor(sq, 16); sq += __shfl_xor(sq, 32);
    float invk = 1.0f / fmaxf(sqrtf(sq), 1e-12f);

    f32x4 s4 = {0.f, 0.f, 0.f, 0.f};
    #pragma unroll
    for (int kk = 0; kk < 8; ++kk) {
        bfrag a = *reinterpret_cast<const bfrag*>(qp + kk * 32);
        s4 = __builtin_amdgcn_mfma_f32_16x16x32_bf16(a, kf[kk], s4, 0, 0, 0);
    }

    const int  j     = r16;
    const bool first = (iw == 0);
    #pragma unroll
    for (int rr = 0; rr < 4; ++rr) {
        int i = g4 * 4 + rr;
        float s = s4[rr] * invk;
        if (j == i + 7) s = -5.0e4f;
        if (j > i + 7 || j >= 14 || (first && j < 7)) s = -3.0e38f;
        s4[rr] = s;
    }
    f32x4 mx = s4;
    #pragma unroll
    for (int off = 8; off; off >>= 1) {
        #pragma unroll
        for (int rr = 0; rr < 4; ++rr) mx[rr] = fmaxf(mx[rr], __shfl_xor(mx[rr], off));
    }
    f32x4 p;
    #pragma unroll
    for (int rr = 0; rr < 4; ++rr) p[rr] = __expf(s4[rr] - mx[rr]);
    f32x4 sm = p;
    #pragma unroll
    for (int off = 8; off; off >>= 1) {
        #pragma unroll
        for (int rr = 0; rr < 4; ++rr) sm[rr] += __shfl_xor(sm[rr], off);
    }
    #pragma unroll
    for (int rr = 0; rr < 4; ++rr) plds[wid][g4 * 4 + rr][j] = p[rr] / sm[rr];
    __syncthreads();

    f32x4 zero4 = {0.f, 0.f, 0.f, 0.f};
    f32x4 oa[7];
    #pragma unroll
    for (int i = 0; i < 7; ++i) oa[i] = zero4;
    for (int jj = 0; jj < 14; ++jj) {
        int vrow = base - 7 + jj;
        if (vrow < 0) vrow = 0;
        ushort4 vr = *reinterpret_cast<const ushort4*>(vbuf + (size_t)vrow * CH + lane * 4);
        f32x4 vvv; vvv[0] = bf2f(vr.x); vvv[1] = bf2f(vr.y); vvv[2] = bf2f(vr.z); vvv[3] = bf2f(vr.w);
        #pragma unroll
        for (int i = 0; i < 7; ++i) {
            float pp = plds[wid][i][jj];
            oa[i][0] += pp * vvv[0]; oa[i][1] += pp * vvv[1];
            oa[i][2] += pp * vvv[2]; oa[i][3] += pp * vvv[3];
        }
    }
    #pragma unroll
    for (int i = 0; i < 7; ++i) {
        ushort4 o; o.x = f2bf(oa[i][0]); o.y = f2bf(oa[i][1]); o.z = f2bf(oa[i][2]); o.w = f2bf(oa[i][3]);
        *reinterpret_cast<ushort4*>(obuf + (size_t)(base + i) * CH + lane * 4) = o;
    }
}

// ---------------- K3: mlp8 — 64-token blocks, 512 thr; parallel stage; W from L2 --
// 1568 blocks (=8*196) x 64 tokens. Wave owns 32 ch x 64 tokens: each W fragment
// feeds 4 MFMAs (vs 2 in mlp6); half the blocks -> half the W L2 traffic.
__global__ __launch_bounds__(512)
void swa_mlp8(const float* __restrict__ x, const u16* __restrict__ abuf,
              const float* __restrict__ ln_g, const float* __restrict__ ln_b,
              const u16* __restrict__ wmb, const float* __restrict__ mbias,
              float* __restrict__ out)
{
    __shared__ u16 xs[64 * 264];                  // LN'd, bf16 (row stride 528 B)
    __shared__ u16 rsdl[64 * 264];                // residual, bf16
    __shared__ float bias[256];
    const int tid  = threadIdx.x;
    const int lane = tid & 63;
    const int wid  = tid >> 6;                    // 0..7 -> 32-ch group
    const int r16  = lane & 15;
    const int g4   = lane >> 4;
    const int swz  = (blockIdx.x & 7) * 196 + (blockIdx.x >> 3);   // 1568 = 8*196
    const int tok0 = swz * 64;

    if (tid < 256) bias[tid] = mbias[tid];

    // ---- parallel stage: 8 threads per token, 64 tokens at once ----
    {
        const int r   = tid >> 3;                 // token row 0..63
        const int sub = tid & 7;
        int tok = tok0 + r;
        int b_  = tok / NPB, rem = tok - b_ * NPB;
        int h = rem / 112, w = rem - h * 112;
        int hs = h + 3;  if (hs >= 112) hs -= 112;    // unshift
        int ws_ = w + 3; if (ws_ >= 112) ws_ -= 112;
        const float* xrow = x + (size_t)tok * CH;
        const u16*   arow = abuf + (size_t)(b_ * NPB + hs * 112 + ws_) * CH;

        f32x4 rv[8];
        float s = 0.f, sq = 0.f;
        #pragma unroll
        for (int j = 0; j < 8; ++j) {
            int cf = sub + 8 * j;                 // 16B chunk (4 channels)
            f32x4   xv = *reinterpret_cast<const f32x4*>(xrow + cf * 4);
            ushort4 av = *reinterpret_cast<const ushort4*>(arow + cf * 4);
            rv[j][0] = xv[0] + bf2f(av.x); rv[j][1] = xv[1] + bf2f(av.y);
            rv[j][2] = xv[2] + bf2f(av.z); rv[j][3] = xv[3] + bf2f(av.w);
            s  += rv[j][0] + rv[j][1] + rv[j][2] + rv[j][3];
            sq += rv[j][0]*rv[j][0] + rv[j][1]*rv[j][1] + rv[j][2]*rv[j][2] + rv[j][3]*rv[j][3];
        }
        s += __shfl_xor(s, 1); sq += __shfl_xor(sq, 1);
        s += __shfl_xor(s, 2); sq += __shfl_xor(sq, 2);
        s += __shfl_xor(s, 4); sq += __shfl_xor(sq, 4);
        float mu  = s * (1.0f / 256.0f);
        float var = sq * (1.0f / 256.0f) - mu * mu;
        float inv = 1.0f / sqrtf(var + 1e-5f);

        char* xb = (char*)xs;
        char* rb = (char*)rsdl;
        #pragma unroll
        for (int j = 0; j < 8; ++j) {
            int cf = sub + 8 * j;
            f32x4 g = *reinterpret_cast<const f32x4*>(ln_g + cf * 4);
            f32x4 b = *reinterpret_cast<const f32x4*>(ln_b + cf * 4);
            uint2 px, pr;
            px.x = pk2((rv[j][0]-mu)*inv*g[0]+b[0], (rv[j][1]-mu)*inv*g[1]+b[1]);
            px.y = pk2((rv[j][2]-mu)*inv*g[2]+b[2], (rv[j][3]-mu)*inv*g[3]+b[3]);
            pr.x = pk2(rv[j][0], rv[j][1]);
            pr.y = pk2(rv[j][2], rv[j][3]);
            *reinterpret_cast<uint2*>(xb + r * 528 + cf * 8) = px;
            *reinterpret_cast<uint2*>(rb + r * 528 + cf * 8) = pr;
        }
    }
    __syncthreads();                              // only barrier

    // ---- GEMM: wave wid -> channels [wid*32, wid*32+32), 64 tokens (4 fj) ----
    f32x4 acc[2][4];
    #pragma unroll
    for (int ct = 0; ct < 2; ++ct)
        #pragma unroll
        for (int fj = 0; fj < 4; ++fj) acc[ct][fj] = (f32x4)0.f;

    #pragma unroll
    for (int kk = 0; kk < 8; ++kk) {
        bfrag bfj[4];
        #pragma unroll
        for (int fj = 0; fj < 4; ++fj)
            bfj[fj] = *reinterpret_cast<const bfrag*>((const char*)xs + (fj * 16 + r16) * 528 + kk * 64 + g4 * 16);
        #pragma unroll
        for (int ct = 0; ct < 2; ++ct) {
            bfrag wf = *reinterpret_cast<const bfrag*>(wmb + (size_t)(wid * 32 + ct * 16 + r16) * CH + kk * 32 + g4 * 8);
            #pragma unroll
            for (int fj = 0; fj < 4; ++fj)
                acc[ct][fj] = __builtin_amdgcn_mfma_f32_16x16x32_bf16(wf, bfj[fj], acc[ct][fj], 0, 0, 0);
        }
    }

    #pragma unroll
    for (int ct = 0; ct < 2; ++ct) {
        int ch = wid * 32 + ct * 16 + g4 * 4;
        f32x4 bb = *reinterpret_cast<const f32x4*>(&bias[ch]);
        #pragma unroll
        for (int fj = 0; fj < 4; ++fj) {
            int tokL = fj * 16 + r16;
            ushort4 rbv = *reinterpret_cast<const ushort4*>((const char*)rsdl + tokL * 528 + ch * 2);
            f32x4 vv;
            vv[0] = gelu_fast(acc[ct][fj][0] + bb[0]) + bf2f(rbv.x);
            vv[1] = gelu_fast(acc[ct][fj][1] + bb[1]) + bf2f(rbv.y);
            vv[2] = gelu_fast(acc[ct][fj][2] + bb[2]) + bf2f(rbv.z);
            vv[3] = gelu_fast(acc[ct][fj][3] + bb[3]) + bf2f(rbv.w);
            *reinterpret_cast<f32x4*>(out + (size_t)(tok0 + tokL) * CH + ch) = vv;
        }
    }
}

extern "C" void kernel_launch(void* const* d_in, const int* in_sizes, int n_in,
                              void* d_out, int out_size, void* d_ws, size_t ws_size,
                              hipStream_t stream)
{
    const float* x     = (const float*)d_in[0];
    const float* ln_g  = (const float*)d_in[1];
    const float* ln_b  = (const float*)d_in[2];
    const float* wq_w  = (const float*)d_in[3];
    const float* wq_b  = (const float*)d_in[4];
    const float* wk_w  = (const float*)d_in[5];
    const float* wk_b  = (const float*)d_in[6];
    const float* wv_w  = (const float*)d_in[7];
    const float* wv_b  = (const float*)d_in[8];
    const float* mlp_w = (const float*)d_in[9];
    const float* mlp_b = (const float*)d_in[10];

    char* ws = (char*)d_ws;
    u16* wcat = (u16*)ws;                       // 768*256 bf16
    u16* wmb  = (u16*)(ws + 393216);            // 256*256 bf16
    u16* xnq  = (u16*)(ws + 524288);            // xn -> q (in-place) -> attn output
    u16* kbuf = (u16*)d_out;                    // k,v live in d_out until mlp rewrites it
    u16* vbuf = (u16*)d_out + (size_t)NTOK * CH;

    swa_prep <<<256,  256, 0, stream>>>(wq_w, wk_w, wv_w, mlp_w, wcat, wmb);
    swa_ln   <<<1568, 256, 0, stream>>>(x, ln_g, ln_b, xnq);
    swa_kv   <<<1568, 512, 0, stream>>>(xnq, wcat, wk_b, wv_b, kbuf, vbuf);
    swa_q    <<<392,  512, 0, stream>>>(xnq, wcat, wq_b);
    swa_attn <<<3584, 256, 0, stream>>>(xnq, kbuf, vbuf, xnq);
    swa_mlp8 <<<1568, 512, 0, stream>>>(x, xnq, ln_g, ln_b, wmb, mlp_b, (float*)d_out);
}